// Round 10
// baseline (227.054 us; speedup 1.0000x reference)
//
#include <hip/hip_runtime.h>
#include <hip/hip_bf16.h>

#define DIM   1024
#define HEADS 16
#define DHEAD 64
#define INNER 1024
#define NSEQ  2048
#define NB    2
#define MROWS (NB * NSEQ)   // 4096
#define QS    (3 * INNER)   // fused qkv row stride

typedef __attribute__((ext_vector_type(8))) short    short8;
typedef __attribute__((ext_vector_type(4))) short    short4v;
typedef __attribute__((ext_vector_type(4))) float    floatx4;
typedef __attribute__((ext_vector_type(8))) _Float16 half8;

#define GLOBAL_AS __attribute__((address_space(1)))
#define LDS_AS    __attribute__((address_space(3)))

static __device__ __forceinline__ short f2h(float f) {
  _Float16 h = (_Float16)f;
  return __builtin_bit_cast(short, h);
}
static __device__ __forceinline__ float h2f(short s) {
  return (float)__builtin_bit_cast(_Float16, s);
}

static __device__ __forceinline__ floatx4 mfma16(short8 a, short8 b, floatx4 c) {
  return __builtin_amdgcn_mfma_f32_16x16x32_f16(
      __builtin_bit_cast(half8, a), __builtin_bit_cast(half8, b), c, 0, 0, 0);
}

// bijective XCD chunk decode
static __device__ __forceinline__ int xcd_work(int bid, int nwg) {
  int q = nwg >> 3, r = nwg & 7;
  int xcd = bid & 7, pos = bid >> 3;
  return (xcd < r ? xcd * (q + 1) : r * (q + 1) + (xcd - r) * q) + pos;
}

// 40 chunks per h; qt = 128-row q-tile (0..15), c = kv chunk of 8 64-row tiles.
__device__ __constant__ signed char kQtTab[40] = {
  15,14,13,12,11,10,9,8,7,6,5,4,3,
  15,14,13,12,11,10,9,8,7,
  15,14,13,12,11,
  15,
  2,6,10,14,
  1,5,9,13,
  0,4,8,12};
__device__ __constant__ signed char kCTab[40] = {
  0,0,0,0,0,0,0,0,0,0,0,0,0,
  1,1,1,1,1,1,1,1,1,
  2,2,2,2,2,
  3,
  0,1,2,3,
  0,1,2,3,
  0,1,2,3};
__device__ __constant__ signed char kSlotTab[16][4] = {
  {36,-1,-1,-1},{32,-1,-1,-1},{28,-1,-1,-1},{12,-1,-1,-1},
  {11,37,-1,-1},{10,33,-1,-1},{ 9,29,-1,-1},{ 8,21,-1,-1},
  { 7,20,38,-1},{ 6,19,34,-1},{ 5,18,30,-1},{ 4,17,26,-1},
  { 3,16,25,39},{ 2,15,24,35},{ 1,14,23,31},{ 0,13,22,27}};

// ------ fused prep: LN (blocks 0..4095) + 3 weight transposes --------------
__global__ __launch_bounds__(256) void prep_kernel(
    const float* __restrict__ x, const float* __restrict__ gamma,
    const float* __restrict__ beta, short* __restrict__ xn,
    const float* __restrict__ wq, const float* __restrict__ wkv,
    const float* __restrict__ wo, short* __restrict__ wqkv_t,
    short* __restrict__ wo_t) {
  __shared__ float tile[32][33];
  int bid = blockIdx.x;
  int t = threadIdx.x;

  if (bid < MROWS) {
    // ---- LayerNorm row ----
    const float4* xr = reinterpret_cast<const float4*>(x + (size_t)bid * DIM);
    float4 v = xr[t];
    float s  = v.x + v.y + v.z + v.w;
    float s2 = v.x * v.x + v.y * v.y + v.z * v.z + v.w * v.w;
#pragma unroll
    for (int off = 1; off < 64; off <<= 1) {
      s  += __shfl_xor(s, off);
      s2 += __shfl_xor(s2, off);
    }
    float* red = &tile[0][0];
    if ((t & 63) == 0) { red[t >> 6] = s; red[(t >> 6) + 4] = s2; }
    __syncthreads();
    s  = red[0] + red[1] + red[2] + red[3];
    s2 = red[4] + red[5] + red[6] + red[7];
    float mu   = s * (1.0f / DIM);
    float var  = s2 * (1.0f / DIM) - mu * mu;
    float rstd = rsqrtf(var + 1e-5f);
    float4 g  = reinterpret_cast<const float4*>(gamma)[t];
    float4 bb = reinterpret_cast<const float4*>(beta)[t];
    short4v o;
    o.x = f2h((v.x - mu) * rstd * g.x + bb.x);
    o.y = f2h((v.y - mu) * rstd * g.y + bb.y);
    o.z = f2h((v.z - mu) * rstd * g.z + bb.z);
    o.w = f2h((v.w - mu) * rstd * g.w + bb.w);
    reinterpret_cast<short4v*>(xn + (size_t)bid * DIM)[t] = o;
    return;
  }

  // ---- weight transpose tile ----
  bid -= MROWS;
  const float* src; short* dst; int Nn, nx;
  if (bid < 1024)      { src = wq;  dst = wqkv_t;                     Nn = 1024; nx = 32; }
  else if (bid < 3072) { bid -= 1024; src = wkv;
                         dst = wqkv_t + (size_t)1024 * 1024;          Nn = 2048; nx = 64; }
  else                 { bid -= 3072; src = wo;  dst = wo_t;          Nn = 1024; nx = 32; }
  int n0 = (bid % nx) * 32, k0 = (bid / nx) * 32;
  int tx = t & 31, ty = t >> 5;
#pragma unroll
  for (int i = 0; i < 32; i += 8)
    tile[ty + i][tx] = src[(size_t)(k0 + ty + i) * Nn + n0 + tx];
  __syncthreads();
#pragma unroll
  for (int i = 0; i < 32; i += 8)
    dst[(size_t)(n0 + ty + i) * 1024 + k0 + tx] = f2h(tile[tx][ty + i]);
}

// ------ GEMM 256x256, BK=64, 8 waves, double-buffered 2-phase pipeline -----
__global__ __launch_bounds__(512) void gemm_bt256(const short* __restrict__ A,
                                                  const short* __restrict__ Bt,
                                                  short* __restrict__ Cout,
                                                  int Nn, int Kk, int NBN,
                                                  float oscale, float oscale2,
                                                  int qsplit) {
  __shared__ __attribute__((aligned(16))) short As[2][256 * 64];
  __shared__ __attribute__((aligned(16))) short Bs[2][256 * 64];

  int wk = xcd_work(blockIdx.x, gridDim.x);
  int bm = wk / NBN, bn = wk % NBN;
  int t = threadIdx.x, lane = t & 63, w = t >> 6;
  int l15 = lane & 15, lhi = lane >> 4;
  int wr = w >> 2, wc = w & 3;

  const short* Ag = A + (size_t)bm * 256 * Kk;
  const short* Bg = Bt + (size_t)bn * 256 * Kk;

  auto stage = [&](int kt, int buf) {
#pragma unroll
    for (int it = 0; it < 4; ++it) {
      int base = it * 512 + w * 64;
      int g = base + lane;
      int row = g >> 3, c8 = (g & 7) << 3;
      __builtin_amdgcn_global_load_lds(
          (const GLOBAL_AS unsigned int*)(Ag + (size_t)row * Kk + kt * 64 + c8),
          (LDS_AS unsigned int*)(&As[buf][base * 8]), 16, 0, 0);
    }
#pragma unroll
    for (int it = 0; it < 4; ++it) {
      int base = it * 512 + w * 64;
      int g = base + lane;
      int row = g >> 3, c8 = (g & 7) << 3;
      __builtin_amdgcn_global_load_lds(
          (const GLOBAL_AS unsigned int*)(Bg + (size_t)row * Kk + kt * 64 + c8),
          (LDS_AS unsigned int*)(&Bs[buf][base * 8]), 16, 0, 0);
    }
  };

  floatx4 acc[8][4] = {};
  int NK = Kk >> 6;

  stage(0, 0);
  __syncthreads();
  int cur = 0;
  for (int kt = 0; kt < NK; ++kt) {
    if (kt + 1 < NK) stage(kt + 1, cur ^ 1);
#pragma unroll
    for (int kc = 0; kc < 2; ++kc) {
      short8 a[8], b[4];
#pragma unroll
      for (int mt = 0; mt < 8; ++mt)
        a[mt] = *reinterpret_cast<const short8*>(
            &As[cur][(wr * 128 + mt * 16 + l15) * 64 + kc * 32 + lhi * 8]);
#pragma unroll
      for (int nt = 0; nt < 4; ++nt)
        b[nt] = *reinterpret_cast<const short8*>(
            &Bs[cur][(wc * 64 + nt * 16 + l15) * 64 + kc * 32 + lhi * 8]);
#pragma unroll
      for (int mt = 0; mt < 8; ++mt)
#pragma unroll
        for (int nt = 0; nt < 4; ++nt)
          acc[mt][nt] = mfma16(a[mt], b[nt], acc[mt][nt]);
    }
    __syncthreads();
    cur ^= 1;
  }

  int row0 = bm * 256 + wr * 128 + lhi * 4;
  int col0 = bn * 256 + wc * 64 + l15;
#pragma unroll
  for (int mt = 0; mt < 8; ++mt)
#pragma unroll
    for (int nt = 0; nt < 4; ++nt) {
      float osc = (bn * 256 + wc * 64 + nt * 16 < qsplit) ? oscale : oscale2;
#pragma unroll
      for (int r = 0; r < 4; ++r) {
        int row = row0 + mt * 16 + r;
        int col = col0 + nt * 16;
        Cout[(size_t)row * Nn + col] = f2h(acc[mt][nt][r] * osc);
      }
    }
}

// --------- GEMM 128x128 (m97-style), linear grid + XCD chunking ------------
template <bool F32OUT>
__global__ __launch_bounds__(256) void gemm_bt(const short* __restrict__ A,
                                               const short* __restrict__ Bt,
                                               void* __restrict__ Cout,
                                               int Nn, int Kk, int NBN,
                                               float oscale) {
  constexpr int BM = 128, BN = 128, BK = 64;
  __shared__ __attribute__((aligned(16))) short As[BM * BK];
  __shared__ __attribute__((aligned(16))) short Bs[BN * BK];
  int wk = xcd_work(blockIdx.x, gridDim.x);
  int bm = wk / NBN, bn = wk % NBN;
  int t = threadIdx.x, lane = t & 63, w = t >> 6;
  int l15 = lane & 15, lhi = lane >> 4;
  int wr = w >> 1, wc = w & 1;
  floatx4 acc[4][4] = {};
  const short* Ag = A + (size_t)bm * BM * Kk;
  const short* Bg = Bt + (size_t)bn * BN * Kk;

  for (int k0 = 0; k0 < Kk; k0 += BK) {
#pragma unroll
    for (int it = 0; it < 4; ++it) {
      int base = it * 256 + w * 64;
      int idx  = base + lane;
      int row  = idx >> 3, kc = (idx & 7) << 3;
      __builtin_amdgcn_global_load_lds(
          (const GLOBAL_AS unsigned int*)(Ag + (size_t)row * Kk + k0 + kc),
          (LDS_AS unsigned int*)(As + base * 8), 16, 0, 0);
    }
#pragma unroll
    for (int it = 0; it < 4; ++it) {
      int base = it * 256 + w * 64;
      int idx  = base + lane;
      int row  = idx >> 3, kc = (idx & 7) << 3;
      __builtin_amdgcn_global_load_lds(
          (const GLOBAL_AS unsigned int*)(Bg + (size_t)row * Kk + k0 + kc),
          (LDS_AS unsigned int*)(Bs + base * 8), 16, 0, 0);
    }
    __syncthreads();
#pragma unroll
    for (int kc = 0; kc < 2; ++kc) {
      short8 a[4], b[4];
#pragma unroll
      for (int mt = 0; mt < 4; ++mt)
        a[mt] = *reinterpret_cast<const short8*>(
            &As[(wr * 64 + mt * 16 + l15) * BK + lhi * 8 + kc * 32]);
#pragma unroll
      for (int nt = 0; nt < 4; ++nt)
        b[nt] = *reinterpret_cast<const short8*>(
            &Bs[(wc * 64 + nt * 16 + l15) * BK + lhi * 8 + kc * 32]);
#pragma unroll
      for (int mt = 0; mt < 4; ++mt)
#pragma unroll
        for (int nt = 0; nt < 4; ++nt)
          acc[mt][nt] = mfma16(a[mt], b[nt], acc[mt][nt]);
    }
    __syncthreads();
  }

  int row0 = bm * BM + wr * 64;
  int col0 = bn * BN + wc * 64;
#pragma unroll
  for (int mt = 0; mt < 4; ++mt)
#pragma unroll
    for (int nt = 0; nt < 4; ++nt)
#pragma unroll
      for (int r = 0; r < 4; ++r) {
        int row = row0 + mt * 16 + lhi * 4 + r;
        int col = col0 + nt * 16 + l15;
        if (F32OUT)
          ((float*)Cout)[(size_t)row * Nn + col] = acc[mt][nt][r] * oscale;
        else
          ((short*)Cout)[(size_t)row * Nn + col] = f2h(acc[mt][nt][r] * oscale);
      }
}

// ----- causal flash attention: 128-row q-tiles, BOTH batches per block -----
__global__ __launch_bounds__(512) void attn_kernel(const short* __restrict__ qkv,
                                                   const float* __restrict__ bias,
                                                   short* __restrict__ ao,
                                                   short* __restrict__ Opart,
                                                   float* __restrict__ mlpart) {
  __shared__ __attribute__((aligned(16))) short Ks[2][2][4096];
  __shared__ __attribute__((aligned(16))) short Vt[2][4096];
  __shared__ __attribute__((aligned(16))) short Ps[128 * 72];

  int p = blockIdx.x;
  int rank = p >> 4, h = p & 15;
  int qt = kQtTab[rank], c = kCTab[rank];
  int tt0 = c * 8;
  int tt1 = 2 * qt + 2; if (tt0 + 8 < tt1) tt1 = tt0 + 8;
  int qb = qt * 128;
  int t = threadIdx.x, lane = t & 63, w = t >> 6;
  int l15 = lane & 15, lhi = lane >> 4;

  short8 qf[2][2];
#pragma unroll
  for (int bb = 0; bb < 2; ++bb) {
    const short* qrow = qkv +
        ((size_t)(bb * NSEQ + qb + w * 16 + l15)) * QS + h * DHEAD + lhi * 8;
    qf[bb][0] = *reinterpret_cast<const short8*>(qrow);
    qf[bb][1] = *reinterpret_cast<const short8*>(qrow + 32);
  }

  int krow = t >> 3;
  int kcg  = (t & 7) ^ (krow & 7);
  int vrr = (t >> 4) * 2, vcc = (t & 15) << 2;
  short4v vr[2][2];

  auto issueK = [&](int tile, int nb) {
#pragma unroll
    for (int bb = 0; bb < 2; ++bb) {
      const short* gp = qkv +
          ((size_t)(bb * NSEQ + tile * 64 + krow)) * QS + INNER + h * DHEAD + kcg * 8;
      __builtin_amdgcn_global_load_lds(
          (const GLOBAL_AS unsigned int*)gp,
          (LDS_AS unsigned int*)(&Ks[nb][bb][0] + (size_t)w * 512), 16, 0, 0);
    }
  };
  auto issueV = [&](int tile) {
#pragma unroll
    for (int bb = 0; bb < 2; ++bb) {
      const short* vp = qkv + ((size_t)(bb * NSEQ + tile * 64 + vrr)) * QS +
                        2 * INNER + h * DHEAD + vcc;
      vr[bb][0] = *reinterpret_cast<const short4v*>(vp);
      vr[bb][1] = *reinterpret_cast<const short4v*>(vp + QS);
    }
  };
  auto writeV = [&]() {
#pragma unroll
    for (int bb = 0; bb < 2; ++bb)
#pragma unroll
      for (int e = 0; e < 4; ++e) {
        int d  = vcc + e;
        int jj = vrr ^ ((d & 7) << 3);
        unsigned int pk = (unsigned short)vr[bb][0][e] |
                          ((unsigned int)(unsigned short)vr[bb][1][e] << 16);
        *reinterpret_cast<unsigned int*>(&Vt[bb][d * 64 + jj]) = pk;
      }
  };
  auto issueB = [&](int tile, floatx4 (&br)[4]) {
    const float* bb0 = bias +
        ((size_t)h * NSEQ + (qb + w * 16 + l15)) * NSEQ + tile * 64 + lhi * 4;
#pragma unroll
    for (int jt = 0; jt < 4; ++jt)
      br[jt] = *reinterpret_cast<const floatx4*>(bb0 + jt * 16);
  };

  float m[2], l[2];
  floatx4 oacc[2][4] = {};
#pragma unroll
  for (int bb = 0; bb < 2; ++bb) { m[bb] = -1e30f; l[bb] = 0.f; }

  int swz = (l15 & 7) << 3;

  auto step = [&](int tt, int KB, floatx4 (&brU)[4], floatx4 (&brN)[4]) {
    bool more = (tt + 1 < tt1);
    if (more) { issueK(tt + 1, KB ^ 1); issueV(tt + 1); issueB(tt + 1, brN); }

#pragma unroll
    for (int bb = 0; bb < 2; ++bb) {
      floatx4 s[4];
#pragma unroll
      for (int jt = 0; jt < 4; ++jt) s[jt] = brU[jt];

#pragma unroll
      for (int jt = 0; jt < 4; ++jt) {
        int ro = (jt * 16 + l15) * 64;
        short8 k0 = *reinterpret_cast<const short8*>(
            &Ks[KB][bb][ro + ((lhi * 8) ^ swz)]);
        short8 k1 = *reinterpret_cast<const short8*>(
            &Ks[KB][bb][ro + ((lhi * 8 + 32) ^ swz)]);
        s[jt] = mfma16(k0, qf[bb][0], s[jt]);
        s[jt] = mfma16(k1, qf[bb][1], s[jt]);
      }

      if (tt >= 2 * qt) {
        int dq = qb + w * 16 + l15 - tt * 64;
#pragma unroll
        for (int jt = 0; jt < 4; ++jt)
#pragma unroll
          for (int r = 0; r < 4; ++r)
            if (jt * 16 + lhi * 4 + r > dq) s[jt][r] = -1e30f;
      }

      float mx = s[0][0];
#pragma unroll
      for (int jt = 0; jt < 4; ++jt)
#pragma unroll
        for (int r = 0; r < 4; ++r) mx = fmaxf(mx, s[jt][r]);
      mx = fmaxf(mx, __shfl_xor(mx, 16));
      mx = fmaxf(mx, __shfl_xor(mx, 32));
      float mnew = fmaxf(m[bb], mx);
      float fac  = __expf(m[bb] - mnew);
      m[bb] = mnew;
      float ps = 0.f;
#pragma unroll
      for (int jt = 0; jt < 4; ++jt)
#pragma unroll
        for (int r = 0; r < 4; ++r) {
          float pv = __expf(s[jt][r] - mnew);
          s[jt][r] = pv;
          ps += pv;
        }
      ps += __shfl_xor(ps, 16);
      ps += __shfl_xor(ps, 32);
      l[bb] = l[bb] * fac + ps;

      float facr[4];
#pragma unroll
      for (int r = 0; r < 4; ++r)
        facr[r] = __shfl(fac, (lane & 48) | (lhi * 4 + r));
#pragma unroll
      for (int dt = 0; dt < 4; ++dt)
#pragma unroll
        for (int r = 0; r < 4; ++r) oacc[bb][dt][r] *= facr[r];

#pragma unroll
      for (int jt = 0; jt < 4; ++jt) {
        short4v pv4;
        pv4.x = f2h(s[jt][0]); pv4.y = f2h(s[jt][1]);
        pv4.z = f2h(s[jt][2]); pv4.w = f2h(s[jt][3]);
        *reinterpret_cast<short4v*>(
            &Ps[(w * 16 + l15) * 72 + jt * 16 + lhi * 4]) = pv4;
      }

#pragma unroll
      for (int jc = 0; jc < 2; ++jc) {
        short8 pf = *reinterpret_cast<const short8*>(
            &Ps[(w * 16 + l15) * 72 + lhi * 8 + jc * 32]);
#pragma unroll
        for (int dt = 0; dt < 4; ++dt) {
          int dd = dt * 16 + l15;
          short8 vf = *reinterpret_cast<const short8*>(
              &Vt[bb][dd * 64 + ((lhi * 8 + jc * 32) ^ swz)]);
          oacc[bb][dt] = mfma16(pf, vf, oacc[bb][dt]);
        }
      }
    }

    if (more) {
      __syncthreads();
      writeV();
      __syncthreads();
    }
  };

  floatx4 brA[4], brB[4];
  issueK(tt0, 0);
  issueV(tt0);
  issueB(tt0, brA);
  __syncthreads();
  writeV();
  __syncthreads();

  int nt = tt1 - tt0;
  for (int i = 0; i < nt; i += 2) {
    step(tt0 + i, 0, brA, brB);
    step(tt0 + i + 1, 1, brB, brA);
  }

  bool single = (tt0 == 0) && (tt1 == 2 * qt + 2);
  if (single) {
#pragma unroll
    for (int bb = 0; bb < 2; ++bb) {
      float linv = 1.f / l[bb];
      float lr[4];
#pragma unroll
      for (int r = 0; r < 4; ++r)
        lr[r] = __shfl(linv, (lane & 48) | (lhi * 4 + r));
#pragma unroll
      for (int dt = 0; dt < 4; ++dt)
#pragma unroll
        for (int r = 0; r < 4; ++r) {
          int row = qb + w * 16 + lhi * 4 + r;
          int col = h * DHEAD + dt * 16 + l15;
          ao[((size_t)(bb * NSEQ + row)) * INNER + col] =
              f2h(oacc[bb][dt][r] * lr[r]);
        }
    }
  } else {
#pragma unroll
    for (int bb = 0; bb < 2; ++bb) {
      size_t pp = ((size_t)h * 40 + rank) * 2 + bb;
      short* Ob = Opart + pp * 8192;
#pragma unroll
      for (int dt = 0; dt < 4; ++dt)
#pragma unroll
        for (int r = 0; r < 4; ++r)
          Ob[(w * 16 + lhi * 4 + r) * 64 + dt * 16 + l15] = f2h(oacc[bb][dt][r]);
      if (lhi == 0) {
        mlpart[pp * 256 + w * 16 + l15] = m[bb];
        mlpart[pp * 256 + 128 + w * 16 + l15] = l[bb];
      }
    }
  }
}

// ---------------- combine 2..4 partials per 128-row q-tile (qt>=4) ---------
__global__ __launch_bounds__(512) void attn_combine(const short* __restrict__ Opart,
                                                    const float* __restrict__ mlpart,
                                                    short* __restrict__ o) {
  int qt = blockIdx.x + 4, h = blockIdx.y, b = blockIdx.z;
  int nc = (2 * qt + 9) >> 3;
  int t = threadIdx.x, row = t >> 2, cg = (t & 3) << 4;

  float mv[4], lv[4];
  float M = -1e30f;
#pragma unroll
  for (int c2 = 0; c2 < 4; ++c2) {
    if (c2 < nc) {
      size_t pp = ((size_t)h * 40 + kSlotTab[qt][c2]) * 2 + b;
      mv[c2] = mlpart[pp * 256 + row];
      lv[c2] = mlpart[pp * 256 + 128 + row];
      M = fmaxf(M, mv[c2]);
    }
  }

  float acc[16] = {};
  float lsum = 0.f;
#pragma unroll
  for (int c2 = 0; c2 < 4; ++c2) {
    if (c2 >= nc) break;
    float wgt = __expf(mv[c2] - M);
    lsum += wgt * lv[c2];
    size_t pp = ((size_t)h * 40 + kSlotTab[qt][c2]) * 2 + b;
    const short8* Or =
        reinterpret_cast<const short8*>(Opart + pp * 8192 + row * 64 + cg);
    short8 a0 = Or[0], a1 = Or[1];
#pragma unroll
    for (int e = 0; e < 8; ++e) {
      acc[e]     += wgt * h2f(a0[e]);
      acc[8 + e] += wgt * h2f(a1[e]);
    }
  }
  float inv = 1.f / lsum;
  short* op = o + ((size_t)(b * NSEQ + qt * 128 + row)) * INNER + h * DHEAD + cg;
  short8 o0, o1;
#pragma unroll
  for (int e = 0; e < 8; ++e) {
    o0[e] = f2h(acc[e] * inv);
    o1[e] = f2h(acc[8 + e] * inv);
  }
  reinterpret_cast<short8*>(op)[0] = o0;
  reinterpret_cast<short8*>(op)[1] = o1;
}

// ---------------------------------------------------------------------------
extern "C" void kernel_launch(void* const* d_in, const int* in_sizes, int n_in,
                              void* d_out, int out_size, void* d_ws, size_t ws_size,
                              hipStream_t stream) {
  const float* x     = (const float*)d_in[0];
  const float* bias  = (const float*)d_in[1];
  const float* gamma = (const float*)d_in[2];
  const float* beta  = (const float*)d_in[3];
  const float* wq    = (const float*)d_in[4];
  const float* wkv   = (const float*)d_in[5];
  const float* wo    = (const float*)d_in[6];
  float* out = (float*)d_out;   // fp32 output

  char* ws = (char*)d_ws;
  const size_t MB = 1024 * 1024;
  short* xn      = (short*)(ws);              // 8 MB  [4096][1024]
  short* wqkv_t  = (short*)(ws + 8  * MB);    // 6 MB  [3072][1024]
  short* wo_t    = (short*)(ws + 14 * MB);    // 2 MB  [1024][1024]
  short* qkv     = (short*)(ws + 16 * MB);    // 24 MB [4096][3072]
  short* Opart   = (short*)(ws + 40 * MB);    // 21 MB fp16 partials
  float* mlpart  = (float*)(ws + 62 * MB);    // 1.3 MB
  short* ao      = xn;                        // reuse xn after qkv GEMM

  // fused LN + 3 weight transposes: 4096 + 1024 + 2048 + 1024 = 8192 blocks
  prep_kernel<<<8192, 256, 0, stream>>>(x, gamma, beta, xn, wq, wkv, wo,
                                        wqkv_t, wo_t);

  // ATTRIBUTION: both GEMMs launched TWICE (idempotent, full overwrite).
  // dur_us - 168.3 = qkv_gemm + out_gemm durations (warm).
  gemm_bt256<<<(MROWS / 256) * (QS / 256), 512, 0, stream>>>(
      xn, wqkv_t, qkv, QS, DIM, QS / 256, 0.125f, 1.0f, 1024);
  gemm_bt256<<<(MROWS / 256) * (QS / 256), 512, 0, stream>>>(
      xn, wqkv_t, qkv, QS, DIM, QS / 256, 0.125f, 1.0f, 1024);

  attn_kernel<<<640, 512, 0, stream>>>(qkv, bias, ao, Opart, mlpart);
  attn_combine<<<dim3(12, HEADS, NB), 512, 0, stream>>>(Opart, mlpart, ao);

  gemm_bt<true><<<(MROWS / 128) * (DIM / 128), 256, 0, stream>>>(
      ao, wo_t, out, DIM, INNER, DIM / 128, 1.0f);
  gemm_bt<true><<<(MROWS / 128) * (DIM / 128), 256, 0, stream>>>(
      ao, wo_t, out, DIM, INNER, DIM / 128, 1.0f);
}

// Round 11
// 151.638 us; speedup vs baseline: 1.4973x; 1.4973x over previous
//
#include <hip/hip_runtime.h>
#include <hip/hip_bf16.h>

#define DIM   1024
#define HEADS 16
#define DHEAD 64
#define INNER 1024
#define NSEQ  2048
#define NB    2
#define MROWS (NB * NSEQ)   // 4096
#define QS    (3 * INNER)   // fused qkv row stride

typedef __attribute__((ext_vector_type(8))) short    short8;
typedef __attribute__((ext_vector_type(4))) short    short4v;
typedef __attribute__((ext_vector_type(4))) float    floatx4;
typedef __attribute__((ext_vector_type(8))) _Float16 half8;

#define GLOBAL_AS __attribute__((address_space(1)))
#define LDS_AS    __attribute__((address_space(3)))

static __device__ __forceinline__ short f2h(float f) {
  _Float16 h = (_Float16)f;
  return __builtin_bit_cast(short, h);
}
static __device__ __forceinline__ float h2f(short s) {
  return (float)__builtin_bit_cast(_Float16, s);
}

static __device__ __forceinline__ floatx4 mfma16(short8 a, short8 b, floatx4 c) {
  return __builtin_amdgcn_mfma_f32_16x16x32_f16(
      __builtin_bit_cast(half8, a), __builtin_bit_cast(half8, b), c, 0, 0, 0);
}

// bijective XCD chunk decode
static __device__ __forceinline__ int xcd_work(int bid, int nwg) {
  int q = nwg >> 3, r = nwg & 7;
  int xcd = bid & 7, pos = bid >> 3;
  return (xcd < r ? xcd * (q + 1) : r * (q + 1) + (xcd - r) * q) + pos;
}

// 40 chunks per h; qt = 128-row q-tile (0..15), c = kv chunk of 8 64-row tiles.
__device__ __constant__ signed char kQtTab[40] = {
  15,14,13,12,11,10,9,8,7,6,5,4,3,
  15,14,13,12,11,10,9,8,7,
  15,14,13,12,11,
  15,
  2,6,10,14,
  1,5,9,13,
  0,4,8,12};
__device__ __constant__ signed char kCTab[40] = {
  0,0,0,0,0,0,0,0,0,0,0,0,0,
  1,1,1,1,1,1,1,1,1,
  2,2,2,2,2,
  3,
  0,1,2,3,
  0,1,2,3,
  0,1,2,3};
__device__ __constant__ signed char kSlotTab[16][4] = {
  {36,-1,-1,-1},{32,-1,-1,-1},{28,-1,-1,-1},{12,-1,-1,-1},
  {11,37,-1,-1},{10,33,-1,-1},{ 9,29,-1,-1},{ 8,21,-1,-1},
  { 7,20,38,-1},{ 6,19,34,-1},{ 5,18,30,-1},{ 4,17,26,-1},
  { 3,16,25,39},{ 2,15,24,35},{ 1,14,23,31},{ 0,13,22,27}};

// ------ fused prep: LN (blocks 0..4095) + 3 weight transposes --------------
__global__ __launch_bounds__(256) void prep_kernel(
    const float* __restrict__ x, const float* __restrict__ gamma,
    const float* __restrict__ beta, short* __restrict__ xn,
    const float* __restrict__ wq, const float* __restrict__ wkv,
    const float* __restrict__ wo, short* __restrict__ wqkv_t,
    short* __restrict__ wo_t) {
  __shared__ float tile[32][33];
  int bid = blockIdx.x;
  int t = threadIdx.x;

  if (bid < MROWS) {
    const float4* xr = reinterpret_cast<const float4*>(x + (size_t)bid * DIM);
    float4 v = xr[t];
    float s  = v.x + v.y + v.z + v.w;
    float s2 = v.x * v.x + v.y * v.y + v.z * v.z + v.w * v.w;
#pragma unroll
    for (int off = 1; off < 64; off <<= 1) {
      s  += __shfl_xor(s, off);
      s2 += __shfl_xor(s2, off);
    }
    float* red = &tile[0][0];
    if ((t & 63) == 0) { red[t >> 6] = s; red[(t >> 6) + 4] = s2; }
    __syncthreads();
    s  = red[0] + red[1] + red[2] + red[3];
    s2 = red[4] + red[5] + red[6] + red[7];
    float mu   = s * (1.0f / DIM);
    float var  = s2 * (1.0f / DIM) - mu * mu;
    float rstd = rsqrtf(var + 1e-5f);
    float4 g  = reinterpret_cast<const float4*>(gamma)[t];
    float4 bb = reinterpret_cast<const float4*>(beta)[t];
    short4v o;
    o.x = f2h((v.x - mu) * rstd * g.x + bb.x);
    o.y = f2h((v.y - mu) * rstd * g.y + bb.y);
    o.z = f2h((v.z - mu) * rstd * g.z + bb.z);
    o.w = f2h((v.w - mu) * rstd * g.w + bb.w);
    reinterpret_cast<short4v*>(xn + (size_t)bid * DIM)[t] = o;
    return;
  }

  bid -= MROWS;
  const float* src; short* dst; int Nn, nx;
  if (bid < 1024)      { src = wq;  dst = wqkv_t;                     Nn = 1024; nx = 32; }
  else if (bid < 3072) { bid -= 1024; src = wkv;
                         dst = wqkv_t + (size_t)1024 * 1024;          Nn = 2048; nx = 64; }
  else                 { bid -= 3072; src = wo;  dst = wo_t;          Nn = 1024; nx = 32; }
  int n0 = (bid % nx) * 32, k0 = (bid / nx) * 32;
  int tx = t & 31, ty = t >> 5;
#pragma unroll
  for (int i = 0; i < 32; i += 8)
    tile[ty + i][tx] = src[(size_t)(k0 + ty + i) * Nn + n0 + tx];
  __syncthreads();
#pragma unroll
  for (int i = 0; i < 32; i += 8)
    dst[(size_t)(n0 + ty + i) * 1024 + k0 + tx] = f2h(tile[tx][ty + i]);
}

// ---- GEMM 128x128, counted-vmcnt double-buffer, XOR-swizzled LDS ----------
// C[M][Nn] = A[M][Kk] * Bt[Nn][Kk]^T. Raw barriers; vmcnt(8) keeps the next
// tile's 8 loads in flight across barriers (T4). Swizzle: linear LDS dest,
// XOR-permuted global source, XOR on read (same involution, rule 21).
template <bool F32OUT>
__global__ __launch_bounds__(256) void gemm_cv(const short* __restrict__ A,
                                               const short* __restrict__ Bt,
                                               void* __restrict__ Cout,
                                               int Nn, int Kk, int NBN,
                                               float oscale, float oscale2,
                                               int qsplit) {
  __shared__ __attribute__((aligned(16))) short As[2][128 * 64];  // 32 KB
  __shared__ __attribute__((aligned(16))) short Bs[2][128 * 64];  // 32 KB
  int wk = xcd_work(blockIdx.x, gridDim.x);
  int bm = wk / NBN, bn = wk % NBN;
  int t = threadIdx.x, lane = t & 63, w = t >> 6;
  int l15 = lane & 15, lhi = lane >> 4;
  int wr = w >> 1, wc = w & 1;
  const short* Ag = A + (size_t)bm * 128 * Kk;
  const short* Bg = Bt + (size_t)bn * 128 * Kk;

  auto stage = [&](int kt, int buf) {
#pragma unroll
    for (int it = 0; it < 4; ++it) {
      int id = it * 256 + t;
      int row = id >> 3;
      int cs = ((id & 7) ^ (row & 7)) << 3;   // pre-swizzled global source
      __builtin_amdgcn_global_load_lds(
          (const GLOBAL_AS unsigned int*)(Ag + (size_t)row * Kk + kt * 64 + cs),
          (LDS_AS unsigned int*)(&As[buf][id * 8]), 16, 0, 0);
    }
#pragma unroll
    for (int it = 0; it < 4; ++it) {
      int id = it * 256 + t;
      int row = id >> 3;
      int cs = ((id & 7) ^ (row & 7)) << 3;
      __builtin_amdgcn_global_load_lds(
          (const GLOBAL_AS unsigned int*)(Bg + (size_t)row * Kk + kt * 64 + cs),
          (LDS_AS unsigned int*)(&Bs[buf][id * 8]), 16, 0, 0);
    }
  };

  floatx4 acc[4][4] = {};
  int NK = Kk >> 6;   // 16 for K=1024

  stage(0, 0);
  stage(1, 1);        // 16 loads outstanding
  for (int kt = 0; kt < NK; ++kt) {
    // wait for THIS tile's loads only; next tile's 8 stay in flight
    if (kt + 1 < NK) asm volatile("s_waitcnt vmcnt(8)" ::: "memory");
    else             asm volatile("s_waitcnt vmcnt(0)" ::: "memory");
    __builtin_amdgcn_s_barrier();          // all waves' stage(kt) visible
    __builtin_amdgcn_sched_barrier(0);

    int buf = kt & 1;
#pragma unroll
    for (int kc = 0; kc < 2; ++kc) {
      short8 a[4], b[4];
#pragma unroll
      for (int mt = 0; mt < 4; ++mt) {
        int row = wr * 64 + mt * 16 + l15;
        int g = (kc * 4 + lhi) ^ (l15 & 7);  // row&7 == l15&7
        a[mt] = *reinterpret_cast<const short8*>(&As[buf][row * 64 + g * 8]);
      }
#pragma unroll
      for (int nt = 0; nt < 4; ++nt) {
        int row = wc * 64 + nt * 16 + l15;
        int g = (kc * 4 + lhi) ^ (l15 & 7);
        b[nt] = *reinterpret_cast<const short8*>(&Bs[buf][row * 64 + g * 8]);
      }
#pragma unroll
      for (int mt = 0; mt < 4; ++mt)
#pragma unroll
        for (int nt = 0; nt < 4; ++nt)
          acc[mt][nt] = mfma16(a[mt], b[nt], acc[mt][nt]);
    }

    asm volatile("s_waitcnt lgkmcnt(0)" ::: "memory");  // my ds_reads complete
    __builtin_amdgcn_sched_barrier(0);
    __builtin_amdgcn_s_barrier();          // everyone done reading buf
    __builtin_amdgcn_sched_barrier(0);
    if (kt + 2 < NK) stage(kt + 2, buf);   // overwrite freed buffer
  }

  int row0 = bm * 128 + wr * 64;
  int col0 = bn * 128 + wc * 64;
#pragma unroll
  for (int mt = 0; mt < 4; ++mt)
#pragma unroll
    for (int nt = 0; nt < 4; ++nt) {
      float osc = (col0 + nt * 16 < qsplit) ? oscale : oscale2;
#pragma unroll
      for (int r = 0; r < 4; ++r) {
        int row = row0 + mt * 16 + lhi * 4 + r;
        int col = col0 + nt * 16 + l15;
        if (F32OUT)
          ((float*)Cout)[(size_t)row * Nn + col] = acc[mt][nt][r] * osc;
        else
          ((short*)Cout)[(size_t)row * Nn + col] = f2h(acc[mt][nt][r] * osc);
      }
    }
}

// ----- causal flash attention: 128-row q-tiles, BOTH batches per block -----
__global__ __launch_bounds__(512) void attn_kernel(const short* __restrict__ qkv,
                                                   const float* __restrict__ bias,
                                                   short* __restrict__ ao,
                                                   short* __restrict__ Opart,
                                                   float* __restrict__ mlpart) {
  __shared__ __attribute__((aligned(16))) short Ks[2][2][4096];
  __shared__ __attribute__((aligned(16))) short Vt[2][4096];
  __shared__ __attribute__((aligned(16))) short Ps[128 * 72];

  int p = blockIdx.x;
  int rank = p >> 4, h = p & 15;
  int qt = kQtTab[rank], c = kCTab[rank];
  int tt0 = c * 8;
  int tt1 = 2 * qt + 2; if (tt0 + 8 < tt1) tt1 = tt0 + 8;
  int qb = qt * 128;
  int t = threadIdx.x, lane = t & 63, w = t >> 6;
  int l15 = lane & 15, lhi = lane >> 4;

  short8 qf[2][2];
#pragma unroll
  for (int bb = 0; bb < 2; ++bb) {
    const short* qrow = qkv +
        ((size_t)(bb * NSEQ + qb + w * 16 + l15)) * QS + h * DHEAD + lhi * 8;
    qf[bb][0] = *reinterpret_cast<const short8*>(qrow);
    qf[bb][1] = *reinterpret_cast<const short8*>(qrow + 32);
  }

  int krow = t >> 3;
  int kcg  = (t & 7) ^ (krow & 7);
  int vrr = (t >> 4) * 2, vcc = (t & 15) << 2;
  short4v vr[2][2];

  auto issueK = [&](int tile, int nb) {
#pragma unroll
    for (int bb = 0; bb < 2; ++bb) {
      const short* gp = qkv +
          ((size_t)(bb * NSEQ + tile * 64 + krow)) * QS + INNER + h * DHEAD + kcg * 8;
      __builtin_amdgcn_global_load_lds(
          (const GLOBAL_AS unsigned int*)gp,
          (LDS_AS unsigned int*)(&Ks[nb][bb][0] + (size_t)w * 512), 16, 0, 0);
    }
  };
  auto issueV = [&](int tile) {
#pragma unroll
    for (int bb = 0; bb < 2; ++bb) {
      const short* vp = qkv + ((size_t)(bb * NSEQ + tile * 64 + vrr)) * QS +
                        2 * INNER + h * DHEAD + vcc;
      vr[bb][0] = *reinterpret_cast<const short4v*>(vp);
      vr[bb][1] = *reinterpret_cast<const short4v*>(vp + QS);
    }
  };
  auto writeV = [&]() {
#pragma unroll
    for (int bb = 0; bb < 2; ++bb)
#pragma unroll
      for (int e = 0; e < 4; ++e) {
        int d  = vcc + e;
        int jj = vrr ^ ((d & 7) << 3);
        unsigned int pk = (unsigned short)vr[bb][0][e] |
                          ((unsigned int)(unsigned short)vr[bb][1][e] << 16);
        *reinterpret_cast<unsigned int*>(&Vt[bb][d * 64 + jj]) = pk;
      }
  };
  auto issueB = [&](int tile, floatx4 (&br)[4]) {
    const float* bb0 = bias +
        ((size_t)h * NSEQ + (qb + w * 16 + l15)) * NSEQ + tile * 64 + lhi * 4;
#pragma unroll
    for (int jt = 0; jt < 4; ++jt)
      br[jt] = *reinterpret_cast<const floatx4*>(bb0 + jt * 16);
  };

  float m[2], l[2];
  floatx4 oacc[2][4] = {};
#pragma unroll
  for (int bb = 0; bb < 2; ++bb) { m[bb] = -1e30f; l[bb] = 0.f; }

  int swz = (l15 & 7) << 3;

  auto step = [&](int tt, int KB, floatx4 (&brU)[4], floatx4 (&brN)[4]) {
    bool more = (tt + 1 < tt1);
    if (more) { issueK(tt + 1, KB ^ 1); issueV(tt + 1); issueB(tt + 1, brN); }

#pragma unroll
    for (int bb = 0; bb < 2; ++bb) {
      floatx4 s[4];
#pragma unroll
      for (int jt = 0; jt < 4; ++jt) s[jt] = brU[jt];

#pragma unroll
      for (int jt = 0; jt < 4; ++jt) {
        int ro = (jt * 16 + l15) * 64;
        short8 k0 = *reinterpret_cast<const short8*>(
            &Ks[KB][bb][ro + ((lhi * 8) ^ swz)]);
        short8 k1 = *reinterpret_cast<const short8*>(
            &Ks[KB][bb][ro + ((lhi * 8 + 32) ^ swz)]);
        s[jt] = mfma16(k0, qf[bb][0], s[jt]);
        s[jt] = mfma16(k1, qf[bb][1], s[jt]);
      }

      if (tt >= 2 * qt) {
        int dq = qb + w * 16 + l15 - tt * 64;
#pragma unroll
        for (int jt = 0; jt < 4; ++jt)
#pragma unroll
          for (int r = 0; r < 4; ++r)
            if (jt * 16 + lhi * 4 + r > dq) s[jt][r] = -1e30f;
      }

      float mx = s[0][0];
#pragma unroll
      for (int jt = 0; jt < 4; ++jt)
#pragma unroll
        for (int r = 0; r < 4; ++r) mx = fmaxf(mx, s[jt][r]);
      mx = fmaxf(mx, __shfl_xor(mx, 16));
      mx = fmaxf(mx, __shfl_xor(mx, 32));
      float mnew = fmaxf(m[bb], mx);
      float fac  = __expf(m[bb] - mnew);
      m[bb] = mnew;
      float ps = 0.f;
#pragma unroll
      for (int jt = 0; jt < 4; ++jt)
#pragma unroll
        for (int r = 0; r < 4; ++r) {
          float pv = __expf(s[jt][r] - mnew);
          s[jt][r] = pv;
          ps += pv;
        }
      ps += __shfl_xor(ps, 16);
      ps += __shfl_xor(ps, 32);
      l[bb] = l[bb] * fac + ps;

      float facr[4];
#pragma unroll
      for (int r = 0; r < 4; ++r)
        facr[r] = __shfl(fac, (lane & 48) | (lhi * 4 + r));
#pragma unroll
      for (int dt = 0; dt < 4; ++dt)
#pragma unroll
        for (int r = 0; r < 4; ++r) oacc[bb][dt][r] *= facr[r];

#pragma unroll
      for (int jt = 0; jt < 4; ++jt) {
        short4v pv4;
        pv4.x = f2h(s[jt][0]); pv4.y = f2h(s[jt][1]);
        pv4.z = f2h(s[jt][2]); pv4.w = f2h(s[jt][3]);
        *reinterpret_cast<short4v*>(
            &Ps[(w * 16 + l15) * 72 + jt * 16 + lhi * 4]) = pv4;
      }

#pragma unroll
      for (int jc = 0; jc < 2; ++jc) {
        short8 pf = *reinterpret_cast<const short8*>(
            &Ps[(w * 16 + l15) * 72 + lhi * 8 + jc * 32]);
#pragma unroll
        for (int dt = 0; dt < 4; ++dt) {
          int dd = dt * 16 + l15;
          short8 vf = *reinterpret_cast<const short8*>(
              &Vt[bb][dd * 64 + ((lhi * 8 + jc * 32) ^ swz)]);
          oacc[bb][dt] = mfma16(pf, vf, oacc[bb][dt]);
        }
      }
    }

    if (more) {
      __syncthreads();
      writeV();
      __syncthreads();
    }
  };

  floatx4 brA[4], brB[4];
  issueK(tt0, 0);
  issueV(tt0);
  issueB(tt0, brA);
  __syncthreads();
  writeV();
  __syncthreads();

  int nt = tt1 - tt0;
  for (int i = 0; i < nt; i += 2) {
    step(tt0 + i, 0, brA, brB);
    step(tt0 + i + 1, 1, brB, brA);
  }

  bool single = (tt0 == 0) && (tt1 == 2 * qt + 2);
  if (single) {
#pragma unroll
    for (int bb = 0; bb < 2; ++bb) {
      float linv = 1.f / l[bb];
      float lr[4];
#pragma unroll
      for (int r = 0; r < 4; ++r)
        lr[r] = __shfl(linv, (lane & 48) | (lhi * 4 + r));
#pragma unroll
      for (int dt = 0; dt < 4; ++dt)
#pragma unroll
        for (int r = 0; r < 4; ++r) {
          int row = qb + w * 16 + lhi * 4 + r;
          int col = h * DHEAD + dt * 16 + l15;
          ao[((size_t)(bb * NSEQ + row)) * INNER + col] =
              f2h(oacc[bb][dt][r] * lr[r]);
        }
    }
  } else {
#pragma unroll
    for (int bb = 0; bb < 2; ++bb) {
      size_t pp = ((size_t)h * 40 + rank) * 2 + bb;
      short* Ob = Opart + pp * 8192;
#pragma unroll
      for (int dt = 0; dt < 4; ++dt)
#pragma unroll
        for (int r = 0; r < 4; ++r)
          Ob[(w * 16 + lhi * 4 + r) * 64 + dt * 16 + l15] = f2h(oacc[bb][dt][r]);
      if (lhi == 0) {
        mlpart[pp * 256 + w * 16 + l15] = m[bb];
        mlpart[pp * 256 + 128 + w * 16 + l15] = l[bb];
      }
    }
  }
}

// ---------------- combine 2..4 partials per 128-row q-tile (qt>=4) ---------
__global__ __launch_bounds__(512) void attn_combine(const short* __restrict__ Opart,
                                                    const float* __restrict__ mlpart,
                                                    short* __restrict__ o) {
  int qt = blockIdx.x + 4, h = blockIdx.y, b = blockIdx.z;
  int nc = (2 * qt + 9) >> 3;
  int t = threadIdx.x, row = t >> 2, cg = (t & 3) << 4;

  float mv[4], lv[4];
  float M = -1e30f;
#pragma unroll
  for (int c2 = 0; c2 < 4; ++c2) {
    if (c2 < nc) {
      size_t pp = ((size_t)h * 40 + kSlotTab[qt][c2]) * 2 + b;
      mv[c2] = mlpart[pp * 256 + row];
      lv[c2] = mlpart[pp * 256 + 128 + row];
      M = fmaxf(M, mv[c2]);
    }
  }

  float acc[16] = {};
  float lsum = 0.f;
#pragma unroll
  for (int c2 = 0; c2 < 4; ++c2) {
    if (c2 >= nc) break;
    float wgt = __expf(mv[c2] - M);
    lsum += wgt * lv[c2];
    size_t pp = ((size_t)h * 40 + kSlotTab[qt][c2]) * 2 + b;
    const short8* Or =
        reinterpret_cast<const short8*>(Opart + pp * 8192 + row * 64 + cg);
    short8 a0 = Or[0], a1 = Or[1];
#pragma unroll
    for (int e = 0; e < 8; ++e) {
      acc[e]     += wgt * h2f(a0[e]);
      acc[8 + e] += wgt * h2f(a1[e]);
    }
  }
  float inv = 1.f / lsum;
  short* op = o + ((size_t)(b * NSEQ + qt * 128 + row)) * INNER + h * DHEAD + cg;
  short8 o0, o1;
#pragma unroll
  for (int e = 0; e < 8; ++e) {
    o0[e] = f2h(acc[e] * inv);
    o1[e] = f2h(acc[8 + e] * inv);
  }
  reinterpret_cast<short8*>(op)[0] = o0;
  reinterpret_cast<short8*>(op)[1] = o1;
}

// ---------------------------------------------------------------------------
extern "C" void kernel_launch(void* const* d_in, const int* in_sizes, int n_in,
                              void* d_out, int out_size, void* d_ws, size_t ws_size,
                              hipStream_t stream) {
  const float* x     = (const float*)d_in[0];
  const float* bias  = (const float*)d_in[1];
  const float* gamma = (const float*)d_in[2];
  const float* beta  = (const float*)d_in[3];
  const float* wq    = (const float*)d_in[4];
  const float* wkv   = (const float*)d_in[5];
  const float* wo    = (const float*)d_in[6];
  float* out = (float*)d_out;   // fp32 output

  char* ws = (char*)d_ws;
  const size_t MB = 1024 * 1024;
  short* xn      = (short*)(ws);              // 8 MB  [4096][1024]
  short* wqkv_t  = (short*)(ws + 8  * MB);    // 6 MB  [3072][1024]
  short* wo_t    = (short*)(ws + 14 * MB);    // 2 MB  [1024][1024]
  short* qkv     = (short*)(ws + 16 * MB);    // 24 MB [4096][3072]
  short* Opart   = (short*)(ws + 40 * MB);    // 21 MB fp16 partials
  float* mlpart  = (float*)(ws + 62 * MB);    // 1.3 MB
  short* ao      = xn;                        // reuse xn after qkv GEMM

  prep_kernel<<<8192, 256, 0, stream>>>(x, gamma, beta, xn, wq, wkv, wo,
                                        wqkv_t, wo_t);

  // qkv projection: 128^2 counted-vmcnt GEMM, grid 32*24 = 768
  gemm_cv<false><<<(MROWS / 128) * (QS / 128), 256, 0, stream>>>(
      xn, wqkv_t, qkv, QS, DIM, QS / 128, 0.125f, 1.0f, 1024);

  attn_kernel<<<640, 512, 0, stream>>>(qkv, bias, ao, Opart, mlpart);
  attn_combine<<<dim3(12, HEADS, NB), 512, 0, stream>>>(Opart, mlpart, ao);

  // out projection: 128^2 counted-vmcnt GEMM, grid 32*8 = 256
  gemm_cv<true><<<(MROWS / 128) * (DIM / 128), 256, 0, stream>>>(
      ao, wo_t, out, DIM, INNER, DIM / 128, 1.0f, 1.0f, 0);
}